// Round 19
// baseline (162.728 us; speedup 1.0000x reference)
//
#include <hip/hip_runtime.h>

// Problem constants
#define TT 2000
#define NN 64
#define CC 512
#define SS 200
#define NCr (NN*CC)      // row stride in floats (t -> t+1) = 32768
#define PF 8             // fallback prefetch depth
#define GD 24            // scan gather-pipeline depth (r19: 16 -> 24)
#define LN2 0.69314718055994530942f

// ---------------- workspace layout (bytes) ----------------
// pbT  : (N, T) float  -> precomputed blank probs exp(lp[t][n][0])
// loss : (N) float
#define OFF_PB   0ull
#define SZ_PB    ((unsigned long long)NN * TT * 4)                // 512,000
#define OFF_LOSS (OFF_PB + SZ_PB)
#define SZ_LOSS  (256ull)
#define WS_NEED  (OFF_LOSS + SZ_LOSS)

// lane l <- lane l-1 (lane 0 <- 0), single VALU op (v_mov_b32_dpp wave_shr:1)
__device__ __forceinline__ float dpp_shr1(float x) {
    return __int_as_float(__builtin_amdgcn_update_dpp(
        0, __float_as_int(x), 0x138 /*WAVE_SHR1*/, 0xF, 0xF, true));
}
__device__ __forceinline__ int dpp_shr1_i(int x) {
    return __builtin_amdgcn_update_dpp(0, x, 0x138, 0xF, 0xF, true);
}

// ---- kernel 0: blank probs pbT[n][t] = exp(lp[t][n][0]) ----
// Separate kernel ON PURPOSE (r16 lesson): folding this into the scan's
// F-pipeline oversubscribes the per-CU line budget (268->316us).
__global__ __launch_bounds__(256, 1)
void ctc_pblank(const float* __restrict__ lp, float* __restrict__ pbT)
{
    const int n = blockIdx.x;
    for (int t = threadIdx.x; t < TT; t += 256)
        pbT[n * TT + t] = __expf(lp[((size_t)t * NN + n) * CC]);
}

// =================== 4-wave pipelined scan, direct gather ===================
// Block = 256 threads = 4 waves; wave w owns states 128w..128w+127, lane l
// owns (even 2L, odd 2L+1) with L = 64w+l. Each lane gathers its ONE label
// prob lp[t][n][c_L] through a GD-deep register pipeline, exp'd at use.
// r18 dead-lane clamp kept (qmask==0 lanes gather the blank line).
// r19: GD 16->24 (+50% in-flight gathers/wave). In-flight HBM-line estimate
// at r18 was ~86/CU vs ~128 MSHR capacity -> headroom for deeper per-wave
// MLP (NOT more waves - r15 refuted that). Slot index for row r = (r-1)%GD;
// 6-phase superloop covers 3 slot-offsets x 2 ring sets.
// Ring / per-lane power-of-2 frames / boundary logic identical to r11/r14.

#define SPIN(tg_) do {                                                        \
    while (__hip_atomic_load(progc, __ATOMIC_ACQUIRE,                         \
                             __HIP_MEMORY_SCOPE_WORKGROUP) < (tg_)) {}        \
} while (0)

#define CONS_ADOPT(lmB_) do {                                                 \
    if (lane0) {                                                              \
        if (!active) logM = (lmB_);                                           \
        else { int dB_ = (lmB_) - logM;                                       \
               if (dB_ > 100) { S0 = 0.f; S1 = 0.f; logM = (lmB_); } }        \
    }                                                                         \
} while (0)

#define CONS_SCE(lmA_, lmB_, E1_, ER_) do {                                   \
    int dA_ = (lmA_) - logM; int dB_ = (lmB_) - logM;                         \
    dA_ = dA_ < -126 ? -126 : (dA_ > 126 ? 126 : dA_);                        \
    dB_ = dB_ < -126 ? -126 : (dB_ > 126 ? 126 : dB_);                        \
    float sA_ = __uint_as_float((unsigned)(dA_ + 127) << 23);                 \
    float sB_ = __uint_as_float((unsigned)(dB_ + 127) << 23);                 \
    if (lane0) { (E1_) = sA_; (ER_) = sB_; }                                  \
} while (0)

#define STEP(u_, RV, SCE) do {                                                \
    float q_  = __expf(G[u_]) * qmask;                                        \
    float pb_ = F[u_];                                                        \
    int rp_ = t + GD; rp_ = rp_ < TT ? rp_ : TT - 1;                          \
    G[u_] = lpc[(size_t)rp_ * NCr];                                           \
    F[u_] = pbn[rp_];                                                         \
    float pin_ = dpp_shr1(S1);                                                \
    if constexpr (CONSQ) pin_ = lane0 ? (RV) : pin_;                          \
    float pe_ = pin_ * (SCE);                                                 \
    float n1_ = (S1 + S0 + allow * pe_) * q_;                                 \
    float n0_ = (S0 + pe_) * pb_;                                             \
    if constexpr (FRZQ) { bool uf_ = t < inlen;                               \
        S1 = uf_ ? n1_ : S1; S0 = uf_ ? n0_ : S0; }                           \
    else { S1 = n1_; S0 = n0_; }                                              \
    if constexpr (PRODQ) { *prodPtr = S1; prodPtr += prodInc; }               \
    ++t;                                                                      \
} while (0)

#define RENORM4 do {                                                          \
    float mx_ = fmaxf(S0, S1);                                                \
    active = mx_ > 0.0f;                                                      \
    int e_ = (int)(__float_as_uint(mx_) >> 23) - 127;                         \
    float sc_ = __uint_as_float((unsigned)(127 - e_) << 23);                  \
    logM += e_; S0 *= sc_; S1 *= sc_;                                         \
} while (0)

#define BOUNDARY4 do {                                                        \
    unsigned long long mk_ = __ballot(active);                                \
    int idx_ = mk_ ? (63 - __builtin_clzll(mk_)) : 0;                         \
    int bc_ = __builtin_amdgcn_readlane(logM, idx_);                          \
    if (!active) logM = bc_;                                                  \
    int pmF_ = dpp_shr1_i(logM);                                              \
    int dd_ = pmF_ - logM;                                                    \
    if (l != 0 && active && dd_ > 100) {                                      \
        S0 = 0.f; S1 = 0.f; logM = pmF_; dd_ = 0; active = false;             \
    }                                                                         \
    dd_ = dd_ < -126 ? -126 : (dd_ > 126 ? 126 : dd_);                        \
    sc7e = __uint_as_float((unsigned)(dd_ + 127) << 23);                      \
} while (0)

// OFF = slot offset (0/8/16); U = ring set used; Lo = set preloaded for next
#define BLOCK8(OFF, U, Lo) do {                                               \
    int lmA_ = 0, lmB_ = 0;                                                   \
    if constexpr (CONSQ) {                                                    \
        if ((bIdx & 3) == 0) { int tg_ = (bIdx + 6) * 8;                      \
            if (tg_ > 1999) tg_ = 1999; SPIN(tg_); }                          \
        int nb_ = bIdx + 1;                                                   \
        float4 ra_ = *(const float4*)(ringVc + 8 * nb_);                      \
        float4 rb_ = *(const float4*)(ringVc + 8 * nb_ + 4);                  \
        rv_##Lo##0 = ra_.x; rv_##Lo##1 = ra_.y;                               \
        rv_##Lo##2 = ra_.z; rv_##Lo##3 = ra_.w;                               \
        rv_##Lo##4 = rb_.x; rv_##Lo##5 = rb_.y;                               \
        rv_##Lo##6 = rb_.z; rv_##Lo##7 = rb_.w;                               \
        lmA_ = ringLMc[bIdx]; lmB_ = ringLMc[bIdx + 1];                       \
    }                                                                         \
    STEP(OFF + 0, rv_##U##0, scE1_##U);                                       \
    STEP(OFF + 1, rv_##U##1, scER_##U);                                       \
    STEP(OFF + 2, rv_##U##2, scER_##U);                                       \
    STEP(OFF + 3, rv_##U##3, scER_##U);                                       \
    STEP(OFF + 4, rv_##U##4, scER_##U);                                       \
    STEP(OFF + 5, rv_##U##5, scER_##U);                                       \
    STEP(OFF + 6, rv_##U##6, scER_##U);                                       \
    STEP(OFF + 7, rv_##U##7, scER_##U);                                       \
    RENORM4;                                                                  \
    if constexpr (CONSQ) { CONS_ADOPT(lmB_); }                                \
    BOUNDARY4;                                                                \
    scE1_##Lo = sc7e; scER_##Lo = sc7e;          /* all waves, all lanes */   \
    if constexpr (CONSQ) { CONS_SCE(lmA_, lmB_, scE1_##Lo, scER_##Lo); }      \
    if constexpr (PRODQ) {                                                    \
        if (l == 63) ringLMp[bIdx + 1] = logM;                                \
        if (lane0) __hip_atomic_store(progp, t - 1, __ATOMIC_RELEASE,         \
                                      __HIP_MEMORY_SCOPE_WORKGROUP);          \
    }                                                                         \
    ++bIdx;                                                                   \
} while (0)

template<int PRODQ, int CONSQ, int FRZQ>
__device__ __forceinline__ void scan4_main(
    int l, int inlen, float allow, float qmask,
    float &S0r, float &S1r, int &logMr, bool activeIn,
    const float* lpc,            // per-lane column pointer: lp + n*CC + cL
    const float* pbn,            // pbT + n*TT
    float* prodPtr, int prodInc,
    int* ringLMp, int* progp,
    const float* ringVc, const int* ringLMc,
    int* progc)
{
    float S0 = S0r, S1 = S1r;
    int   logM = logMr;
    bool  active = activeIn;
    float sc7e = 1.0f;
    const bool lane0 = (l == 0);
    int t = 1, bIdx = 0;

    // GD-deep gather pipeline: rows 1..GD (one float per lane per slot)
    float G[GD], F[GD];
    #pragma unroll
    for (int u = 0; u < GD; ++u) {
        G[u] = lpc[(size_t)(1 + u) * NCr];
        F[u] = pbn[1 + u];
    }

    // double-buffered ring data + scale factors
    float rv_a0=0.f,rv_a1=0.f,rv_a2=0.f,rv_a3=0.f,rv_a4=0.f,rv_a5=0.f,rv_a6=0.f,rv_a7=0.f;
    float rv_b0=0.f,rv_b1=0.f,rv_b2=0.f,rv_b3=0.f,rv_b4=0.f,rv_b5=0.f,rv_b6=0.f,rv_b7=0.f;
    float scE1_a=1.f, scER_a=1.f, scE1_b=1.f, scER_b=1.f;

    if constexpr (CONSQ) {
        SPIN(48);                                  // establishes 6-block skew
        float4 ra = *(const float4*)(ringVc + 0);
        float4 rb = *(const float4*)(ringVc + 4);
        rv_a0=ra.x; rv_a1=ra.y; rv_a2=ra.z; rv_a3=ra.w;
        rv_a4=rb.x; rv_a5=rb.y; rv_a6=rb.z; rv_a7=rb.w;
        int lmA0 = ringLMc[0], lmB0 = ringLMc[0];
        CONS_ADOPT(lmB0);
        CONS_SCE(lmA0, lmB0, scE1_a, scER_a);
    }

    // 249 full 8-step blocks: 41 x 6-phase superloop + 3 explicit blocks.
    // Block b uses ring set (b even ? a : b), slot offset (b % 3) * 8.
    for (int it = 0; it < 41; ++it) {
        BLOCK8( 0, a, b);
        BLOCK8( 8, b, a);
        BLOCK8(16, a, b);
        BLOCK8( 0, b, a);
        BLOCK8( 8, a, b);
        BLOCK8(16, b, a);
    }
    BLOCK8( 0, a, b);   // block 246
    BLOCK8( 8, b, a);   // block 247
    BLOCK8(16, a, b);   // block 248 (preloads ring set b for the tail)
    // tail t=1993..1999 (7 steps): slot for row r = (r-1)%24 -> slots 0..6
    STEP(0, rv_b0, scE1_b);
    STEP(1, rv_b1, scER_b);
    STEP(2, rv_b2, scER_b);
    STEP(3, rv_b3, scER_b);
    STEP(4, rv_b4, scER_b);
    STEP(5, rv_b5, scER_b);
    STEP(6, rv_b6, scER_b);
    if constexpr (PRODQ) {
        if (lane0) __hip_atomic_store(progp, 1999, __ATOMIC_RELEASE,
                                      __HIP_MEMORY_SCOPE_WORKGROUP);
    }

    S0r = S0; S1r = S1; logMr = logM;
}

__global__ __launch_bounds__(256, 1)
void ctc_scan4(const float*  __restrict__ lp,
               const float*  __restrict__ pbT,
               const int*    __restrict__ targets,
               const int*    __restrict__ in_len,
               const int*    __restrict__ tgt_len,
               float*        __restrict__ loss_ws)
{
    const int n   = blockIdx.x;
    const int tid = threadIdx.x;
    const int w   = tid >> 6;
    const int l   = tid & 63;
    const int L   = tid;                 // global state-pair index

    __shared__ __align__(16) float ringV[3][2048];
    __shared__ int   ringLM[3][256];
    __shared__ int   prog[4];
    __shared__ float trash[64];
    __shared__ float aE[256], aO[256];
    __shared__ int   lmS[256];

    if (tid < 3) { prog[tid] = 0; ringLM[tid][0] = 0; ringV[tid][0] = 0.f; }

    const int tl    = tgt_len[n];
    const int inlen = in_len[n];

    // label class + skip-allow for odd state 2L+1 (label position L)
    int posc = L < SS ? L : SS - 1;
    int c    = targets[n * SS + posc];
    int pp   = (L - 1) < 0 ? 0 : ((L - 1) < SS ? L - 1 : SS - 1);
    float allow = (L >= 1 && c != targets[n * SS + pp]) ? 1.f : 0.f;
    float qmask = (L < tl) ? 1.f : 0.f;  // odd state 2L+1 valid iff L < tl

    float S0 = 0.f, S1 = 0.f;
    bool active = false;
    if (w == 0 && l == 0) {
        const float* row0 = lp + (size_t)n * CC;
        S0 = __expf(row0[0]);            // state 0: blank
        S1 = __expf(row0[c]);            // state 1: first label (c=targets[n][0])
        active = true;
    }
    int logM = 0;

    __syncthreads();                     // LDS init visible to all waves

    // Dead-lane clamp (r18): qmask==0 lanes gather the blank line (col 0).
    const int   cg  = (qmask > 0.f) ? c : 0;
    const float* lpc = lp  + (size_t)n * CC + cg;  // per-lane column, row 0
    const float* pbn = pbT + (size_t)n * TT;

    float* prodPtr = nullptr; int prodInc = 0;
    int *ringLMp = nullptr, *progp = nullptr, *progc = nullptr;
    const float* ringVc = nullptr; const int* ringLMc = nullptr;
    if (w < 3) {
        prodPtr = (l == 63) ? &ringV[w][1] : &trash[l];
        prodInc = (l == 63) ? 1 : 0;
        ringLMp = ringLM[w]; progp = &prog[w];
    }
    if (w > 0) {
        ringVc = ringV[w - 1]; ringLMc = ringLM[w - 1]; progc = &prog[w - 1];
    }

    const bool fastlen = (inlen >= TT);
    if (w == 0) {
        if (fastlen) scan4_main<1,0,0>(l, inlen, allow, qmask, S0, S1, logM, active,
                lpc, pbn, prodPtr, prodInc, ringLMp, progp, ringVc, ringLMc, progc);
        else         scan4_main<1,0,1>(l, inlen, allow, qmask, S0, S1, logM, active,
                lpc, pbn, prodPtr, prodInc, ringLMp, progp, ringVc, ringLMc, progc);
    } else if (w < 3) {
        if (fastlen) scan4_main<1,1,0>(l, inlen, allow, qmask, S0, S1, logM, active,
                lpc, pbn, prodPtr, prodInc, ringLMp, progp, ringVc, ringLMc, progc);
        else         scan4_main<1,1,1>(l, inlen, allow, qmask, S0, S1, logM, active,
                lpc, pbn, prodPtr, prodInc, ringLMp, progp, ringVc, ringLMc, progc);
    } else {
        if (fastlen) scan4_main<0,1,0>(l, inlen, allow, qmask, S0, S1, logM, active,
                lpc, pbn, prodPtr, prodInc, ringLMp, progp, ringVc, ringLMc, progc);
        else         scan4_main<0,1,1>(l, inlen, allow, qmask, S0, S1, logM, active,
                lpc, pbn, prodPtr, prodInc, ringLMp, progp, ringVc, ringLMc, progc);
    }

    // epilogue
    aE[L] = S0; aO[L] = S1; lmS[L] = logM;
    __syncthreads();
    if (tid == 0) {
        int L1 = tl - 1, L2 = tl;        // odd state 2tl-1, even state 2tl
        float la = __logf(aO[L1]) + (float)lmS[L1] * LN2;
        float lb = __logf(aE[L2]) + (float)lmS[L2] * LN2;
        float m  = fmaxf(la, lb);
        float loss = -(m + __logf(__expf(la - m) + __expf(lb - m)));
        loss_ws[n] = loss / (float)tl;
    }
}

#undef SPIN
#undef CONS_ADOPT
#undef CONS_SCE
#undef STEP
#undef RENORM4
#undef BOUNDARY4
#undef BLOCK8

// ---------------- fallback: round-5 single-kernel scan (proven) ------------
__global__ __launch_bounds__(64, 1)
void ctc_alpha_fb(const float* __restrict__ lp, const int* __restrict__ targets,
                  const int* __restrict__ in_len, const int* __restrict__ tgt_len,
                  float* __restrict__ loss_ws)
{
    const int n = blockIdx.x;
    const int l = threadIdx.x;
    __shared__ float dumpS[512];
    __shared__ float lmArr[64];
    const int tl   = tgt_len[n];
    const int smax = 2 * tl;
    int   cls[4];
    float allowm[4];
    #pragma unroll
    for (int q = 0; q < 4; ++q) {
        int s    = 8 * l + 2 * q + 1;
        int pos  = (s - 1) >> 1;
        int posc = pos < SS ? pos : SS - 1;
        int c    = targets[n * SS + posc];
        int pp   = pos - 1 < 0 ? 0 : (pos - 1 < SS ? pos - 1 : SS - 1);
        int cp   = targets[n * SS + pp];
        cls[q]    = c;
        allowm[q] = (pos >= 1 && c != cp) ? 1.0f : 0.0f;
    }
    float m0=(8*l+0<=smax)?1.f:0.f, m1=(8*l+1<=smax)?1.f:0.f;
    float m2=(8*l+2<=smax)?1.f:0.f, m3=(8*l+3<=smax)?1.f:0.f;
    float m4=(8*l+4<=smax)?1.f:0.f, m5=(8*l+5<=smax)?1.f:0.f;
    float m6=(8*l+6<=smax)?1.f:0.f, m7=(8*l+7<=smax)?1.f:0.f;
    const int inlen = in_len[n];
    const float* base = lp + (size_t)n * CC;
    float S0=0.f,S1=0.f,S2=0.f,S3=0.f,S4=0.f,S5=0.f,S6=0.f,S7=0.f;
    bool active = (l == 0);
    if (l == 0) { S0 = __expf(base[0]); S1 = __expf(base[cls[0]]); }
    float logM = 0.0f;
    float Gb[PF], G0[PF], G1[PF], G2[PF], G3[PF];
    #pragma unroll
    for (int u = 0; u < PF; ++u) {
        const float* r = base + (size_t)(1 + u) * NCr;
        Gb[u]=r[0]; G0[u]=r[cls[0]]; G1[u]=r[cls[1]]; G2[u]=r[cls[2]]; G3[u]=r[cls[3]];
    }
    int t = 1;
#define STEPF(u) do {                                                         \
    float pb=__expf(Gb[u]), q0=__expf(G0[u]), q1=__expf(G1[u]),               \
          q2=__expf(G2[u]), q3=__expf(G3[u]);                                 \
    int rowpf = (t + PF < TT) ? (t + PF) : (TT - 1);                          \
    const float* r_ = base + (size_t)rowpf * NCr;                             \
    Gb[u]=r_[0]; G0[u]=r_[cls[0]]; G1[u]=r_[cls[1]];                          \
    G2[u]=r_[cls[2]]; G3[u]=r_[cls[3]];                                       \
    float p7 = __shfl_up(S7, 1);                                              \
    float fm = __shfl_up(logM, 1);                                            \
    if (l == 0) p7 = 0.0f;                                                    \
    if (!active && p7 > 0.0f) { logM = fm; active = true; }                   \
    float dd = fminf(fmaxf(fm - logM, -126.0f), 127.0f);                      \
    p7 *= __uint_as_float((unsigned)((int)dd + 127) << 23);                   \
    float n7=(S7+S6+allowm[3]*S5)*q3*m7;                                      \
    float n6=(S6+S5)*pb*m6;                                                   \
    float n5=(S5+S4+allowm[2]*S3)*q2*m5;                                      \
    float n4=(S4+S3)*pb*m4;                                                   \
    float n3=(S3+S2+allowm[1]*S1)*q1*m3;                                      \
    float n2=(S2+S1)*pb*m2;                                                   \
    float n1=(S1+S0+allowm[0]*p7)*q0*m1;                                      \
    float n0=(S0+p7)*pb*m0;                                                   \
    bool upd = t < inlen;                                                     \
    S7=upd?n7:S7; S6=upd?n6:S6; S5=upd?n5:S5; S4=upd?n4:S4;                   \
    S3=upd?n3:S3; S2=upd?n2:S2; S1=upd?n1:S1; S0=upd?n0:S0;                   \
    ++t;                                                                      \
} while (0)
#define RENORMF do {                                                          \
    float mx = fmaxf(fmaxf(fmaxf(S0,S1),fmaxf(S2,S3)),                        \
                     fmaxf(fmaxf(S4,S5),fmaxf(S6,S7)));                       \
    int e = (mx > 0.0f) ? ((int)(__float_as_uint(mx) >> 23) - 127) : 0;       \
    float sc = __uint_as_float((unsigned)(127 - e) << 23);                    \
    logM += (float)e;                                                         \
    S0*=sc;S1*=sc;S2*=sc;S3*=sc;S4*=sc;S5*=sc;S6*=sc;S7*=sc;                  \
} while (0)
    for (int tb = 0; tb < 249; ++tb) {
        STEPF(0); STEPF(1); STEPF(2); STEPF(3);
        STEPF(4); STEPF(5); STEPF(6); STEPF(7);
        RENORMF;
    }
    STEPF(0); STEPF(1); STEPF(2); STEPF(3); STEPF(4); STEPF(5); STEPF(6);
#undef STEPF
#undef RENORMF
    __syncthreads();
    dumpS[8*l+0]=S0; dumpS[8*l+1]=S1; dumpS[8*l+2]=S2; dumpS[8*l+3]=S3;
    dumpS[8*l+4]=S4; dumpS[8*l+5]=S5; dumpS[8*l+6]=S6; dumpS[8*l+7]=S7;
    lmArr[l] = logM;
    __syncthreads();
    if (l == 0) {
        int sA = 2 * tl - 1, sB = 2 * tl;
        float a  = dumpS[sA];
        float b  = dumpS[sB];
        float la = __logf(a) + lmArr[sA >> 3] * LN2;
        float lb = __logf(b) + lmArr[sB >> 3] * LN2;
        float m  = fmaxf(la, lb);
        float loss = -(m + __logf(__expf(la - m) + __expf(lb - m)));
        loss_ws[n] = loss / (float)tl;
    }
}

__global__ void ctc_reduce(const float* __restrict__ loss_ws, float* __restrict__ out)
{
    float v = loss_ws[threadIdx.x];
    #pragma unroll
    for (int off = 32; off > 0; off >>= 1)
        v += __shfl_down(v, off);
    if (threadIdx.x == 0)
        out[0] = v / (float)NN;
}

extern "C" void kernel_launch(void* const* d_in, const int* in_sizes, int n_in,
                              void* d_out, int out_size, void* d_ws, size_t ws_size,
                              hipStream_t stream)
{
    const float* lp      = (const float*)d_in[0];
    const int*   targets = (const int*)d_in[1];
    const int*   in_len  = (const int*)d_in[2];
    const int*   tgt_len = (const int*)d_in[3];
    float*       out     = (float*)d_out;
    char*        ws      = (char*)d_ws;

    if (ws_size >= WS_NEED) {
        float* pbT    = (float*)(ws + OFF_PB);
        float* lossws = (float*)(ws + OFF_LOSS);
        hipLaunchKernelGGL(ctc_pblank, dim3(NN), dim3(256), 0, stream, lp, pbT);
        hipLaunchKernelGGL(ctc_scan4,  dim3(NN), dim3(256), 0, stream,
                           lp, pbT, targets, in_len, tgt_len, lossws);
        hipLaunchKernelGGL(ctc_reduce, dim3(1), dim3(64), 0, stream, lossws, out);
    } else {
        float* lossws = (float*)ws;   // only 256 B needed
        hipLaunchKernelGGL(ctc_alpha_fb, dim3(NN), dim3(64), 0, stream,
                           lp, targets, in_len, tgt_len, lossws);
        hipLaunchKernelGGL(ctc_reduce,   dim3(1),  dim3(64), 0, stream, lossws, out);
    }
}

// Round 20
// 158.636 us; speedup vs baseline: 1.0258x; 1.0258x over previous
//
#include <hip/hip_runtime.h>

// Problem constants
#define TT 2000
#define NN 64
#define CC 512
#define SS 200
#define NCr (NN*CC)      // row stride in floats (t -> t+1) = 32768
#define PF 8             // fallback prefetch depth
#define GD 16            // scan gather-pipeline depth (r19's GD=24: no gain, 2x FETCH)
#define LN2 0.69314718055994530942f

// ---------------- workspace layout (bytes) ----------------
// pbT  : (N, T) float  -> precomputed blank probs exp(lp[t][n][0])
// loss : (N) float
#define OFF_PB   0ull
#define SZ_PB    ((unsigned long long)NN * TT * 4)                // 512,000
#define OFF_LOSS (OFF_PB + SZ_PB)
#define SZ_LOSS  (256ull)
#define WS_NEED  (OFF_LOSS + SZ_LOSS)

// lane l <- lane l-1 (lane 0 <- 0), single VALU op (v_mov_b32_dpp wave_shr:1)
__device__ __forceinline__ float dpp_shr1(float x) {
    return __int_as_float(__builtin_amdgcn_update_dpp(
        0, __float_as_int(x), 0x138 /*WAVE_SHR1*/, 0xF, 0xF, true));
}
__device__ __forceinline__ int dpp_shr1_i(int x) {
    return __builtin_amdgcn_update_dpp(0, x, 0x138, 0xF, 0xF, true);
}

// ---- kernel 0: blank probs pbT[n][t] = exp(lp[t][n][0]) ----
// Separate kernel ON PURPOSE (r16 lesson): folding this into the scan's
// F-pipeline oversubscribes the per-CU line budget (268->316us).
__global__ __launch_bounds__(256, 1)
void ctc_pblank(const float* __restrict__ lp, float* __restrict__ pbT)
{
    const int n = blockIdx.x;
    for (int t = threadIdx.x; t < TT; t += 256)
        pbT[n * TT + t] = __expf(lp[((size_t)t * NN + n) * CC]);
}

// =================== 4-wave pipelined scan, direct gather ===================
// Block = 256 threads = 4 waves; wave w owns states 128w..128w+127, lane l
// owns (even 2L, odd 2L+1) with L = 64w+l. Each lane gathers its ONE label
// prob lp[t][n][c_L] through a 16-deep register pipeline, exp'd at use.
// Dead-lane clamp (r18): qmask==0 lanes gather the blank line (broadcast).
// Refutation ledger: 2 scans/block ✗ (r15 MSHR contention), GD=24 ✗ (r19,
// no gain + 2x FETCH), blank-fused ✗ (r16), HBM compacted stream ≈ (r11),
// cross-block producer-consumer ✗ (r12 acquire-invalidate storm).
// Ring / per-lane power-of-2 frames / boundary logic proven absmax 0.0.

#define SPIN(tg_) do {                                                        \
    while (__hip_atomic_load(progc, __ATOMIC_ACQUIRE,                         \
                             __HIP_MEMORY_SCOPE_WORKGROUP) < (tg_)) {}        \
} while (0)

#define CONS_ADOPT(lmB_) do {                                                 \
    if (lane0) {                                                              \
        if (!active) logM = (lmB_);                                           \
        else { int dB_ = (lmB_) - logM;                                       \
               if (dB_ > 100) { S0 = 0.f; S1 = 0.f; logM = (lmB_); } }        \
    }                                                                         \
} while (0)

#define CONS_SCE(lmA_, lmB_, E1_, ER_) do {                                   \
    int dA_ = (lmA_) - logM; int dB_ = (lmB_) - logM;                         \
    dA_ = dA_ < -126 ? -126 : (dA_ > 126 ? 126 : dA_);                        \
    dB_ = dB_ < -126 ? -126 : (dB_ > 126 ? 126 : dB_);                        \
    float sA_ = __uint_as_float((unsigned)(dA_ + 127) << 23);                 \
    float sB_ = __uint_as_float((unsigned)(dB_ + 127) << 23);                 \
    if (lane0) { (E1_) = sA_; (ER_) = sB_; }                                  \
} while (0)

#define STEP(u_, RV, SCE) do {                                                \
    float q_  = __expf(G[u_]) * qmask;                                        \
    float pb_ = F[u_];                                                        \
    int rp_ = t + GD; rp_ = rp_ < TT ? rp_ : TT - 1;                          \
    G[u_] = lpc[(size_t)rp_ * NCr];                                           \
    F[u_] = pbn[rp_];                                                         \
    float pin_ = dpp_shr1(S1);                                                \
    if constexpr (CONSQ) pin_ = lane0 ? (RV) : pin_;                          \
    float pe_ = pin_ * (SCE);                                                 \
    float n1_ = (S1 + S0 + allow * pe_) * q_;                                 \
    float n0_ = (S0 + pe_) * pb_;                                             \
    if constexpr (FRZQ) { bool uf_ = t < inlen;                               \
        S1 = uf_ ? n1_ : S1; S0 = uf_ ? n0_ : S0; }                           \
    else { S1 = n1_; S0 = n0_; }                                              \
    if constexpr (PRODQ) { *prodPtr = S1; prodPtr += prodInc; }               \
    ++t;                                                                      \
} while (0)

#define RENORM4 do {                                                          \
    float mx_ = fmaxf(S0, S1);                                                \
    active = mx_ > 0.0f;                                                      \
    int e_ = (int)(__float_as_uint(mx_) >> 23) - 127;                         \
    float sc_ = __uint_as_float((unsigned)(127 - e_) << 23);                  \
    logM += e_; S0 *= sc_; S1 *= sc_;                                         \
} while (0)

#define BOUNDARY4 do {                                                        \
    unsigned long long mk_ = __ballot(active);                                \
    int idx_ = mk_ ? (63 - __builtin_clzll(mk_)) : 0;                         \
    int bc_ = __builtin_amdgcn_readlane(logM, idx_);                          \
    if (!active) logM = bc_;                                                  \
    int pmF_ = dpp_shr1_i(logM);                                              \
    int dd_ = pmF_ - logM;                                                    \
    if (l != 0 && active && dd_ > 100) {                                      \
        S0 = 0.f; S1 = 0.f; logM = pmF_; dd_ = 0; active = false;             \
    }                                                                         \
    dd_ = dd_ < -126 ? -126 : (dd_ > 126 ? 126 : dd_);                        \
    sc7e = __uint_as_float((unsigned)(dd_ + 127) << 23);                      \
} while (0)

// OFF = slot offset (0 or 8); U = ring set used; Lo = set preloaded for next
#define BLOCK8(OFF, U, Lo) do {                                               \
    int lmA_ = 0, lmB_ = 0;                                                   \
    if constexpr (CONSQ) {                                                    \
        if ((bIdx & 3) == 0) { int tg_ = (bIdx + 6) * 8;                      \
            if (tg_ > 1999) tg_ = 1999; SPIN(tg_); }                          \
        int nb_ = bIdx + 1;                                                   \
        float4 ra_ = *(const float4*)(ringVc + 8 * nb_);                      \
        float4 rb_ = *(const float4*)(ringVc + 8 * nb_ + 4);                  \
        rv_##Lo##0 = ra_.x; rv_##Lo##1 = ra_.y;                               \
        rv_##Lo##2 = ra_.z; rv_##Lo##3 = ra_.w;                               \
        rv_##Lo##4 = rb_.x; rv_##Lo##5 = rb_.y;                               \
        rv_##Lo##6 = rb_.z; rv_##Lo##7 = rb_.w;                               \
        lmA_ = ringLMc[bIdx]; lmB_ = ringLMc[bIdx + 1];                       \
    }                                                                         \
    STEP(OFF + 0, rv_##U##0, scE1_##U);                                       \
    STEP(OFF + 1, rv_##U##1, scER_##U);                                       \
    STEP(OFF + 2, rv_##U##2, scER_##U);                                       \
    STEP(OFF + 3, rv_##U##3, scER_##U);                                       \
    STEP(OFF + 4, rv_##U##4, scER_##U);                                       \
    STEP(OFF + 5, rv_##U##5, scER_##U);                                       \
    STEP(OFF + 6, rv_##U##6, scER_##U);                                       \
    STEP(OFF + 7, rv_##U##7, scER_##U);                                       \
    RENORM4;                                                                  \
    if constexpr (CONSQ) { CONS_ADOPT(lmB_); }                                \
    BOUNDARY4;                                                                \
    scE1_##Lo = sc7e; scER_##Lo = sc7e;          /* all waves, all lanes */   \
    if constexpr (CONSQ) { CONS_SCE(lmA_, lmB_, scE1_##Lo, scER_##Lo); }      \
    if constexpr (PRODQ) {                                                    \
        if (l == 63) ringLMp[bIdx + 1] = logM;                                \
        if (lane0) __hip_atomic_store(progp, t - 1, __ATOMIC_RELEASE,         \
                                      __HIP_MEMORY_SCOPE_WORKGROUP);          \
    }                                                                         \
    ++bIdx;                                                                   \
} while (0)

template<int PRODQ, int CONSQ, int FRZQ>
__device__ __forceinline__ void scan4_main(
    int l, int inlen, float allow, float qmask,
    float &S0r, float &S1r, int &logMr, bool activeIn,
    const float* lpc,            // per-lane column pointer: lp + n*CC + cL
    const float* pbn,            // pbT + n*TT
    float* prodPtr, int prodInc,
    int* ringLMp, int* progp,
    const float* ringVc, const int* ringLMc,
    int* progc)
{
    float S0 = S0r, S1 = S1r;
    int   logM = logMr;
    bool  active = activeIn;
    float sc7e = 1.0f;
    const bool lane0 = (l == 0);
    int t = 1, bIdx = 0;

    // GD-deep gather pipeline: rows 1..GD (one float per lane per slot)
    float G[GD], F[GD];
    #pragma unroll
    for (int u = 0; u < GD; ++u) {
        G[u] = lpc[(size_t)(1 + u) * NCr];
        F[u] = pbn[1 + u];
    }

    // double-buffered ring data + scale factors
    float rv_a0=0.f,rv_a1=0.f,rv_a2=0.f,rv_a3=0.f,rv_a4=0.f,rv_a5=0.f,rv_a6=0.f,rv_a7=0.f;
    float rv_b0=0.f,rv_b1=0.f,rv_b2=0.f,rv_b3=0.f,rv_b4=0.f,rv_b5=0.f,rv_b6=0.f,rv_b7=0.f;
    float scE1_a=1.f, scER_a=1.f, scE1_b=1.f, scER_b=1.f;

    if constexpr (CONSQ) {
        SPIN(48);                                  // establishes 6-block skew
        float4 ra = *(const float4*)(ringVc + 0);
        float4 rb = *(const float4*)(ringVc + 4);
        rv_a0=ra.x; rv_a1=ra.y; rv_a2=ra.z; rv_a3=ra.w;
        rv_a4=rb.x; rv_a5=rb.y; rv_a6=rb.z; rv_a7=rb.w;
        int lmA0 = ringLMc[0], lmB0 = ringLMc[0];
        CONS_ADOPT(lmB0);
        CONS_SCE(lmA0, lmB0, scE1_a, scER_a);
    }

    for (int it = 0; it < 124; ++it) {
        BLOCK8(0, a, b);
        BLOCK8(8, b, a);
    }
    // block 248 (t=1985..1992): slots 0..7; CONS preloads ring set b
    BLOCK8(0, a, b);
    // tail t=1993..1999 (7 steps): slots 8..14
    STEP( 8, rv_b0, scE1_b);
    STEP( 9, rv_b1, scER_b);
    STEP(10, rv_b2, scER_b);
    STEP(11, rv_b3, scER_b);
    STEP(12, rv_b4, scER_b);
    STEP(13, rv_b5, scER_b);
    STEP(14, rv_b6, scER_b);
    if constexpr (PRODQ) {
        if (lane0) __hip_atomic_store(progp, 1999, __ATOMIC_RELEASE,
                                      __HIP_MEMORY_SCOPE_WORKGROUP);
    }

    S0r = S0; S1r = S1; logMr = logM;
}

__global__ __launch_bounds__(256, 1)
void ctc_scan4(const float*  __restrict__ lp,
               const float*  __restrict__ pbT,
               const int*    __restrict__ targets,
               const int*    __restrict__ in_len,
               const int*    __restrict__ tgt_len,
               float*        __restrict__ loss_ws)
{
    const int n   = blockIdx.x;
    const int tid = threadIdx.x;
    const int w   = tid >> 6;
    const int l   = tid & 63;
    const int L   = tid;                 // global state-pair index

    __shared__ __align__(16) float ringV[3][2048];
    __shared__ int   ringLM[3][256];
    __shared__ int   prog[4];
    __shared__ float trash[64];
    __shared__ float aE[256], aO[256];
    __shared__ int   lmS[256];

    if (tid < 3) { prog[tid] = 0; ringLM[tid][0] = 0; ringV[tid][0] = 0.f; }

    const int tl    = tgt_len[n];
    const int inlen = in_len[n];

    // label class + skip-allow for odd state 2L+1 (label position L)
    int posc = L < SS ? L : SS - 1;
    int c    = targets[n * SS + posc];
    int pp   = (L - 1) < 0 ? 0 : ((L - 1) < SS ? L - 1 : SS - 1);
    float allow = (L >= 1 && c != targets[n * SS + pp]) ? 1.f : 0.f;
    float qmask = (L < tl) ? 1.f : 0.f;  // odd state 2L+1 valid iff L < tl

    float S0 = 0.f, S1 = 0.f;
    bool active = false;
    if (w == 0 && l == 0) {
        const float* row0 = lp + (size_t)n * CC;
        S0 = __expf(row0[0]);            // state 0: blank
        S1 = __expf(row0[c]);            // state 1: first label (c=targets[n][0])
        active = true;
    }
    int logM = 0;

    __syncthreads();                     // LDS init visible to all waves

    // Dead-lane clamp (r18): qmask==0 lanes gather the blank line (col 0).
    const int   cg  = (qmask > 0.f) ? c : 0;
    const float* lpc = lp  + (size_t)n * CC + cg;  // per-lane column, row 0
    const float* pbn = pbT + (size_t)n * TT;

    float* prodPtr = nullptr; int prodInc = 0;
    int *ringLMp = nullptr, *progp = nullptr, *progc = nullptr;
    const float* ringVc = nullptr; const int* ringLMc = nullptr;
    if (w < 3) {
        prodPtr = (l == 63) ? &ringV[w][1] : &trash[l];
        prodInc = (l == 63) ? 1 : 0;
        ringLMp = ringLM[w]; progp = &prog[w];
    }
    if (w > 0) {
        ringVc = ringV[w - 1]; ringLMc = ringLM[w - 1]; progc = &prog[w - 1];
    }

    const bool fastlen = (inlen >= TT);
    if (w == 0) {
        if (fastlen) scan4_main<1,0,0>(l, inlen, allow, qmask, S0, S1, logM, active,
                lpc, pbn, prodPtr, prodInc, ringLMp, progp, ringVc, ringLMc, progc);
        else         scan4_main<1,0,1>(l, inlen, allow, qmask, S0, S1, logM, active,
                lpc, pbn, prodPtr, prodInc, ringLMp, progp, ringVc, ringLMc, progc);
    } else if (w < 3) {
        if (fastlen) scan4_main<1,1,0>(l, inlen, allow, qmask, S0, S1, logM, active,
                lpc, pbn, prodPtr, prodInc, ringLMp, progp, ringVc, ringLMc, progc);
        else         scan4_main<1,1,1>(l, inlen, allow, qmask, S0, S1, logM, active,
                lpc, pbn, prodPtr, prodInc, ringLMp, progp, ringVc, ringLMc, progc);
    } else {
        if (fastlen) scan4_main<0,1,0>(l, inlen, allow, qmask, S0, S1, logM, active,
                lpc, pbn, prodPtr, prodInc, ringLMp, progp, ringVc, ringLMc, progc);
        else         scan4_main<0,1,1>(l, inlen, allow, qmask, S0, S1, logM, active,
                lpc, pbn, prodPtr, prodInc, ringLMp, progp, ringVc, ringLMc, progc);
    }

    // epilogue
    aE[L] = S0; aO[L] = S1; lmS[L] = logM;
    __syncthreads();
    if (tid == 0) {
        int L1 = tl - 1, L2 = tl;        // odd state 2tl-1, even state 2tl
        float la = __logf(aO[L1]) + (float)lmS[L1] * LN2;
        float lb = __logf(aE[L2]) + (float)lmS[L2] * LN2;
        float m  = fmaxf(la, lb);
        float loss = -(m + __logf(__expf(la - m) + __expf(lb - m)));
        loss_ws[n] = loss / (float)tl;
    }
}

#undef SPIN
#undef CONS_ADOPT
#undef CONS_SCE
#undef STEP
#undef RENORM4
#undef BOUNDARY4
#undef BLOCK8

// ---------------- fallback: round-5 single-kernel scan (proven) ------------
__global__ __launch_bounds__(64, 1)
void ctc_alpha_fb(const float* __restrict__ lp, const int* __restrict__ targets,
                  const int* __restrict__ in_len, const int* __restrict__ tgt_len,
                  float* __restrict__ loss_ws)
{
    const int n = blockIdx.x;
    const int l = threadIdx.x;
    __shared__ float dumpS[512];
    __shared__ float lmArr[64];
    const int tl   = tgt_len[n];
    const int smax = 2 * tl;
    int   cls[4];
    float allowm[4];
    #pragma unroll
    for (int q = 0; q < 4; ++q) {
        int s    = 8 * l + 2 * q + 1;
        int pos  = (s - 1) >> 1;
        int posc = pos < SS ? pos : SS - 1;
        int c    = targets[n * SS + posc];
        int pp   = pos - 1 < 0 ? 0 : (pos - 1 < SS ? pos - 1 : SS - 1);
        int cp   = targets[n * SS + pp];
        cls[q]    = c;
        allowm[q] = (pos >= 1 && c != cp) ? 1.0f : 0.0f;
    }
    float m0=(8*l+0<=smax)?1.f:0.f, m1=(8*l+1<=smax)?1.f:0.f;
    float m2=(8*l+2<=smax)?1.f:0.f, m3=(8*l+3<=smax)?1.f:0.f;
    float m4=(8*l+4<=smax)?1.f:0.f, m5=(8*l+5<=smax)?1.f:0.f;
    float m6=(8*l+6<=smax)?1.f:0.f, m7=(8*l+7<=smax)?1.f:0.f;
    const int inlen = in_len[n];
    const float* base = lp + (size_t)n * CC;
    float S0=0.f,S1=0.f,S2=0.f,S3=0.f,S4=0.f,S5=0.f,S6=0.f,S7=0.f;
    bool active = (l == 0);
    if (l == 0) { S0 = __expf(base[0]); S1 = __expf(base[cls[0]]); }
    float logM = 0.0f;
    float Gb[PF], G0[PF], G1[PF], G2[PF], G3[PF];
    #pragma unroll
    for (int u = 0; u < PF; ++u) {
        const float* r = base + (size_t)(1 + u) * NCr;
        Gb[u]=r[0]; G0[u]=r[cls[0]]; G1[u]=r[cls[1]]; G2[u]=r[cls[2]]; G3[u]=r[cls[3]];
    }
    int t = 1;
#define STEPF(u) do {                                                         \
    float pb=__expf(Gb[u]), q0=__expf(G0[u]), q1=__expf(G1[u]),               \
          q2=__expf(G2[u]), q3=__expf(G3[u]);                                 \
    int rowpf = (t + PF < TT) ? (t + PF) : (TT - 1);                          \
    const float* r_ = base + (size_t)rowpf * NCr;                             \
    Gb[u]=r_[0]; G0[u]=r_[cls[0]]; G1[u]=r_[cls[1]];                          \
    G2[u]=r_[cls[2]]; G3[u]=r_[cls[3]];                                       \
    float p7 = __shfl_up(S7, 1);                                              \
    float fm = __shfl_up(logM, 1);                                            \
    if (l == 0) p7 = 0.0f;                                                    \
    if (!active && p7 > 0.0f) { logM = fm; active = true; }                   \
    float dd = fminf(fmaxf(fm - logM, -126.0f), 127.0f);                      \
    p7 *= __uint_as_float((unsigned)((int)dd + 127) << 23);                   \
    float n7=(S7+S6+allowm[3]*S5)*q3*m7;                                      \
    float n6=(S6+S5)*pb*m6;                                                   \
    float n5=(S5+S4+allowm[2]*S3)*q2*m5;                                      \
    float n4=(S4+S3)*pb*m4;                                                   \
    float n3=(S3+S2+allowm[1]*S1)*q1*m3;                                      \
    float n2=(S2+S1)*pb*m2;                                                   \
    float n1=(S1+S0+allowm[0]*p7)*q0*m1;                                      \
    float n0=(S0+p7)*pb*m0;                                                   \
    bool upd = t < inlen;                                                     \
    S7=upd?n7:S7; S6=upd?n6:S6; S5=upd?n5:S5; S4=upd?n4:S4;                   \
    S3=upd?n3:S3; S2=upd?n2:S2; S1=upd?n1:S1; S0=upd?n0:S0;                   \
    ++t;                                                                      \
} while (0)
#define RENORMF do {                                                          \
    float mx = fmaxf(fmaxf(fmaxf(S0,S1),fmaxf(S2,S3)),                        \
                     fmaxf(fmaxf(S4,S5),fmaxf(S6,S7)));                       \
    int e = (mx > 0.0f) ? ((int)(__float_as_uint(mx) >> 23) - 127) : 0;       \
    float sc = __uint_as_float((unsigned)(127 - e) << 23);                    \
    logM += (float)e;                                                         \
    S0*=sc;S1*=sc;S2*=sc;S3*=sc;S4*=sc;S5*=sc;S6*=sc;S7*=sc;                  \
} while (0)
    for (int tb = 0; tb < 249; ++tb) {
        STEPF(0); STEPF(1); STEPF(2); STEPF(3);
        STEPF(4); STEPF(5); STEPF(6); STEPF(7);
        RENORMF;
    }
    STEPF(0); STEPF(1); STEPF(2); STEPF(3); STEPF(4); STEPF(5); STEPF(6);
#undef STEPF
#undef RENORMF
    __syncthreads();
    dumpS[8*l+0]=S0; dumpS[8*l+1]=S1; dumpS[8*l+2]=S2; dumpS[8*l+3]=S3;
    dumpS[8*l+4]=S4; dumpS[8*l+5]=S5; dumpS[8*l+6]=S6; dumpS[8*l+7]=S7;
    lmArr[l] = logM;
    __syncthreads();
    if (l == 0) {
        int sA = 2 * tl - 1, sB = 2 * tl;
        float a  = dumpS[sA];
        float b  = dumpS[sB];
        float la = __logf(a) + lmArr[sA >> 3] * LN2;
        float lb = __logf(b) + lmArr[sB >> 3] * LN2;
        float m  = fmaxf(la, lb);
        float loss = -(m + __logf(__expf(la - m) + __expf(lb - m)));
        loss_ws[n] = loss / (float)tl;
    }
}

__global__ void ctc_reduce(const float* __restrict__ loss_ws, float* __restrict__ out)
{
    float v = loss_ws[threadIdx.x];
    #pragma unroll
    for (int off = 32; off > 0; off >>= 1)
        v += __shfl_down(v, off);
    if (threadIdx.x == 0)
        out[0] = v / (float)NN;
}

extern "C" void kernel_launch(void* const* d_in, const int* in_sizes, int n_in,
                              void* d_out, int out_size, void* d_ws, size_t ws_size,
                              hipStream_t stream)
{
    const float* lp      = (const float*)d_in[0];
    const int*   targets = (const int*)d_in[1];
    const int*   in_len  = (const int*)d_in[2];
    const int*   tgt_len = (const int*)d_in[3];
    float*       out     = (float*)d_out;
    char*        ws      = (char*)d_ws;

    if (ws_size >= WS_NEED) {
        float* pbT    = (float*)(ws + OFF_PB);
        float* lossws = (float*)(ws + OFF_LOSS);
        hipLaunchKernelGGL(ctc_pblank, dim3(NN), dim3(256), 0, stream, lp, pbT);
        hipLaunchKernelGGL(ctc_scan4,  dim3(NN), dim3(256), 0, stream,
                           lp, pbT, targets, in_len, tgt_len, lossws);
        hipLaunchKernelGGL(ctc_reduce, dim3(1), dim3(64), 0, stream, lossws, out);
    } else {
        float* lossws = (float*)ws;   // only 256 B needed
        hipLaunchKernelGGL(ctc_alpha_fb, dim3(NN), dim3(64), 0, stream,
                           lp, targets, in_len, tgt_len, lossws);
        hipLaunchKernelGGL(ctc_reduce,   dim3(1),  dim3(64), 0, stream, lossws, out);
    }
}